// Round 1
// 3036.486 us; speedup vs baseline: 1.3125x; 1.3125x over previous
//
#include <hip/hip_runtime.h>
#include <cstddef>

#define BB 64
#define PP 196
#define ENCD 2048
#define DECD 512
#define ATTD 512
#define EMBD 512
#define VOC 9490
#define NPAD 9536  // VOC padded to 64
#define TDEC 20
#define F2STR 2560  // F2 row: [att2 512 | gate 2048]

using u16 = unsigned short;
using short8 = __attribute__((ext_vector_type(8))) short;   // 8 bf16 (4 VGPRs)
using f32x16 = __attribute__((ext_vector_type(16))) float;  // 32x32 acc

__device__ __forceinline__ float sigmoidf_(float x) { return 1.f / (1.f + __expf(-x)); }

// ---- fp32 -> bf16 RNE, and hi/lo split (x ~= hi + lo, err ~2^-17 |x|) -----
__device__ __forceinline__ unsigned rne_bf(float x) {
  unsigned u = __float_as_uint(x);
  return (u + 0x7FFFu + ((u >> 16) & 1u)) >> 16;
}
__device__ __forceinline__ void split_bf(float x, u16& h, u16& l) {
  unsigned hu = rne_bf(x);
  h = (u16)hu;
  float hf = __uint_as_float(hu << 16);
  l = (u16)rne_bf(x - hf);
}
__device__ __forceinline__ uint4 pack8(const u16* s) {
  uint4 r;
  r.x = (unsigned)s[0] | ((unsigned)s[1] << 16);
  r.y = (unsigned)s[2] | ((unsigned)s[3] << 16);
  r.z = (unsigned)s[4] | ((unsigned)s[5] << 16);
  r.w = (unsigned)s[6] | ((unsigned)s[7] << 16);
  return r;
}

// Swizzled elem offset into a 64x64 u16 LDS tile: row stride 128B = 8 x 16B
// blocks; block index XOR row&7 -> conflict-free b128 write AND read.
#define LADDRE(row, bk) (((row) << 6) + ((((bk) ^ ((row)&7))) << 3))

// ---- one-time: W[K][N] fp32 -> WT_hi/WT_lo [Npad][K] bf16 (transposed) -----
__global__ __launch_bounds__(256) void convT_kernel(const float* __restrict__ W,
                                                    int K, int N,
                                                    u16* __restrict__ Th,
                                                    u16* __restrict__ Tl) {
  __shared__ u16 ht[64][66], lt[64][66];
  int t = threadIdx.x;
  int k0 = blockIdx.x * 64, n0 = blockIdx.y * 64;
  int nl = t & 63, kq = t >> 6;
  int n = n0 + nl;
#pragma unroll
  for (int i = 0; i < 16; ++i) {
    int k = kq * 16 + i;
    float v = (n < N) ? W[(size_t)(k0 + k) * N + n] : 0.f;
    u16 h, l;
    split_bf(v, h, l);
    ht[k][nl] = h;
    lt[k][nl] = l;
  }
  __syncthreads();
  int n2 = t >> 2, q = t & 3;
  u16 h16[16], l16[16];
#pragma unroll
  for (int i = 0; i < 16; ++i) {
    h16[i] = ht[q * 16 + i][n2];
    l16[i] = lt[q * 16 + i][n2];
  }
  size_t ob = (size_t)(n0 + n2) * K + k0 + q * 16;
  *(uint4*)(Th + ob) = pack8(h16);
  *(uint4*)(Th + ob + 8) = pack8(h16 + 8);
  *(uint4*)(Tl + ob) = pack8(l16);
  *(uint4*)(Tl + ob + 8) = pack8(l16 + 8);
}

// ---- att1 = enc(b,k,p)^T @ W_enc_att + bias, split-bf16 MFMA --------------
// M = B*P = 12544 (196 row-tiles of 64, spanning b), N = 512, K = 2048.
// Block 256 thr = 4 waves (2x2), each wave one 32x32 tile via 32x32x16 bf16.
__global__ __launch_bounds__(256) void att1_mfma(const float* __restrict__ enc,
                                                 const u16* __restrict__ BTh,
                                                 const u16* __restrict__ BTl,
                                                 const float* __restrict__ bea,
                                                 float* __restrict__ att1) {
  __shared__ u16 Ah[64 * 64], Al[64 * 64], Bh[64 * 64], Bl[64 * 64];
  int t = threadIdx.x;
  int a0 = blockIdx.x * 64;
  int rowbase = blockIdx.y * 64;
  // A staging: thread -> (row ar, 16-k chunk akc); strided loads (coalesced
  // across lanes: consecutive p at fixed k), transpose+split in regs.
  int ar = t & 63, akc = t >> 6;
  int r = rowbase + ar;
  int ab = r / PP;
  int ap = r - ab * PP;
  const float* asrc = enc + (size_t)ab * (ENCD * PP) + ap;
  // B staging: thread -> (row bn, 16-k quarter bq); 32B contiguous per array.
  int bn = t >> 2, bq = t & 3;
  const u16* bsh = BTh + (size_t)(a0 + bn) * ENCD + bq * 16;
  const u16* bsl = BTl + (size_t)(a0 + bn) * ENCD + bq * 16;
  int lane = t & 63;
  int wr = (t >> 7) & 1, wc = (t >> 6) & 1;
  int l31 = lane & 31, lh = lane >> 5;
  f32x16 acc;
#pragma unroll
  for (int i = 0; i < 16; ++i) acc[i] = 0.f;

  for (int k0 = 0; k0 < ENCD; k0 += 64) {
    float av[16];
#pragma unroll
    for (int i = 0; i < 16; ++i) av[i] = asrc[(size_t)(k0 + akc * 16 + i) * PP];
    u16 h[16], l[16];
#pragma unroll
    for (int i = 0; i < 16; ++i) split_bf(av[i], h[i], l[i]);
    uint4 b0 = *(const uint4*)(bsh + k0);
    uint4 b1 = *(const uint4*)(bsh + k0 + 8);
    uint4 b2 = *(const uint4*)(bsl + k0);
    uint4 b3 = *(const uint4*)(bsl + k0 + 8);
    __syncthreads();  // previous iteration's fragment reads done
    *(uint4*)(Ah + LADDRE(ar, akc * 2)) = pack8(h);
    *(uint4*)(Ah + LADDRE(ar, akc * 2 + 1)) = pack8(h + 8);
    *(uint4*)(Al + LADDRE(ar, akc * 2)) = pack8(l);
    *(uint4*)(Al + LADDRE(ar, akc * 2 + 1)) = pack8(l + 8);
    *(uint4*)(Bh + LADDRE(bn, bq * 2)) = b0;
    *(uint4*)(Bh + LADDRE(bn, bq * 2 + 1)) = b1;
    *(uint4*)(Bl + LADDRE(bn, bq * 2)) = b2;
    *(uint4*)(Bl + LADDRE(bn, bq * 2 + 1)) = b3;
    __syncthreads();
#pragma unroll
    for (int ks = 0; ks < 4; ++ks) {
      int bk = ks * 2 + lh;
      short8 a_h = *(const short8*)(Ah + LADDRE(wr * 32 + l31, bk));
      short8 a_l = *(const short8*)(Al + LADDRE(wr * 32 + l31, bk));
      short8 b_h = *(const short8*)(Bh + LADDRE(wc * 32 + l31, bk));
      short8 b_l = *(const short8*)(Bl + LADDRE(wc * 32 + l31, bk));
      acc = __builtin_amdgcn_mfma_f32_32x32x16_bf16(a_h, b_h, acc, 0, 0, 0);
      acc = __builtin_amdgcn_mfma_f32_32x32x16_bf16(a_h, b_l, acc, 0, 0, 0);
      acc = __builtin_amdgcn_mfma_f32_32x32x16_bf16(a_l, b_h, acc, 0, 0, 0);
    }
  }
  // C/D layout (verified): col = lane&31, row = (g&3) + 8*(g>>2) + 4*(lane>>5)
  int col = a0 + wc * 32 + l31;
  float bv = bea[col];
#pragma unroll
  for (int g = 0; g < 16; ++g) {
    int row = rowbase + wr * 32 + (g & 3) + 8 * (g >> 2) + 4 * lh;
    att1[(size_t)row * ATTD + col] = acc[g] + bv;
  }
}

// ---- preds = Hfc(1280x512) @ W_fc + b_fc, split-bf16 MFMA -----------------
__global__ __launch_bounds__(256) void fc_mfma(const float* __restrict__ Hfc,
                                               const u16* __restrict__ BTh,
                                               const u16* __restrict__ BTl,
                                               const float* __restrict__ bfc,
                                               float* __restrict__ preds) {
  __shared__ u16 Ah[64 * 64], Al[64 * 64], Bh[64 * 64], Bl[64 * 64];
  int t = threadIdx.x;
  int n0 = blockIdx.x * 64;
  int rowbase = blockIdx.y * 64;  // one t-step per row-tile
  int ar = t >> 2, aq = t & 3;
  const float* asrc = Hfc + (size_t)(rowbase + ar) * DECD + aq * 16;
  int bn = t >> 2, bq = t & 3;
  const u16* bsh = BTh + (size_t)(n0 + bn) * DECD + bq * 16;
  const u16* bsl = BTl + (size_t)(n0 + bn) * DECD + bq * 16;
  int lane = t & 63;
  int wr = (t >> 7) & 1, wc = (t >> 6) & 1;
  int l31 = lane & 31, lh = lane >> 5;
  f32x16 acc;
#pragma unroll
  for (int i = 0; i < 16; ++i) acc[i] = 0.f;

  for (int k0 = 0; k0 < DECD; k0 += 64) {
    float av[16];
    *(float4*)(av + 0) = *(const float4*)(asrc + k0);
    *(float4*)(av + 4) = *(const float4*)(asrc + k0 + 4);
    *(float4*)(av + 8) = *(const float4*)(asrc + k0 + 8);
    *(float4*)(av + 12) = *(const float4*)(asrc + k0 + 12);
    u16 h[16], l[16];
#pragma unroll
    for (int i = 0; i < 16; ++i) split_bf(av[i], h[i], l[i]);
    uint4 b0 = *(const uint4*)(bsh + k0);
    uint4 b1 = *(const uint4*)(bsh + k0 + 8);
    uint4 b2 = *(const uint4*)(bsl + k0);
    uint4 b3 = *(const uint4*)(bsl + k0 + 8);
    __syncthreads();
    *(uint4*)(Ah + LADDRE(ar, aq * 2)) = pack8(h);
    *(uint4*)(Ah + LADDRE(ar, aq * 2 + 1)) = pack8(h + 8);
    *(uint4*)(Al + LADDRE(ar, aq * 2)) = pack8(l);
    *(uint4*)(Al + LADDRE(ar, aq * 2 + 1)) = pack8(l + 8);
    *(uint4*)(Bh + LADDRE(bn, bq * 2)) = b0;
    *(uint4*)(Bh + LADDRE(bn, bq * 2 + 1)) = b1;
    *(uint4*)(Bl + LADDRE(bn, bq * 2)) = b2;
    *(uint4*)(Bl + LADDRE(bn, bq * 2 + 1)) = b3;
    __syncthreads();
#pragma unroll
    for (int ks = 0; ks < 4; ++ks) {
      int bk = ks * 2 + lh;
      short8 a_h = *(const short8*)(Ah + LADDRE(wr * 32 + l31, bk));
      short8 a_l = *(const short8*)(Al + LADDRE(wr * 32 + l31, bk));
      short8 b_h = *(const short8*)(Bh + LADDRE(wc * 32 + l31, bk));
      short8 b_l = *(const short8*)(Bl + LADDRE(wc * 32 + l31, bk));
      acc = __builtin_amdgcn_mfma_f32_32x32x16_bf16(a_h, b_h, acc, 0, 0, 0);
      acc = __builtin_amdgcn_mfma_f32_32x32x16_bf16(a_h, b_l, acc, 0, 0, 0);
      acc = __builtin_amdgcn_mfma_f32_32x32x16_bf16(a_l, b_h, acc, 0, 0, 0);
    }
  }
  int col = n0 + wc * 32 + l31;
  if (col < VOC) {
    float bv = bfc[col];
#pragma unroll
    for (int g = 0; g < 16; ++g) {
      int row = rowbase + wr * 32 + (g & 3) + 8 * (g >> 2) + 4 * lh;
      preds[(size_t)(row & 63) * (TDEC * VOC) + (size_t)(row >> 6) * VOC + col] =
          acc[g] + bv;
    }
  }
}

// ---------------- mean over P of encoder_out rows (B*ENC rows of 196) -------
__global__ __launch_bounds__(256) void mean_kernel(const float* __restrict__ enc,
                                                   float* __restrict__ mean) {
  int row = blockIdx.x * 4 + (threadIdx.x >> 6);
  int lane = threadIdx.x & 63;
  const float* r = enc + (size_t)row * PP;
  float v = r[lane] + r[lane + 64] + r[lane + 128];
  if (lane < 4) v += r[lane + 192];
#pragma unroll
  for (int off = 32; off; off >>= 1) v += __shfl_down(v, off);
  if (lane == 0) mean[row] = v * (1.f / 196.f);
}

// ---------------- 64-row x 64-col GEMM, k-split atomic (init h0/c0) ---------
__global__ __launch_bounds__(256) void gemm64_atomic(
    const float* __restrict__ A, int lda, const float* __restrict__ W, int ldw,
    float* __restrict__ C, int ldc, const float* __restrict__ bias0, int kchunk) {
  __shared__ __align__(16) float As[16][68];
  int tid = threadIdx.x;
  int my = tid >> 4, nx = tid & 15;
  int am = tid >> 2, ak = (tid & 3) << 2;
  int n0 = blockIdx.x * 64;
  int k0s = blockIdx.y * kchunk, k0e = k0s + kchunk;
  float acc[4][4] = {};
  for (int k0 = k0s; k0 < k0e; k0 += 16) {
    float4 a4 = *(const float4*)(A + (size_t)am * lda + k0 + ak);
    As[ak + 0][am] = a4.x;
    As[ak + 1][am] = a4.y;
    As[ak + 2][am] = a4.z;
    As[ak + 3][am] = a4.w;
    __syncthreads();
    const float* wp = W + (size_t)k0 * ldw + n0 + (nx << 2);
#pragma unroll
    for (int kk = 0; kk < 16; ++kk) {
      float4 av = *(const float4*)&As[kk][my << 2];
      float4 wv = *(const float4*)(wp + (size_t)kk * ldw);
      acc[0][0] = fmaf(av.x, wv.x, acc[0][0]); acc[0][1] = fmaf(av.x, wv.y, acc[0][1]);
      acc[0][2] = fmaf(av.x, wv.z, acc[0][2]); acc[0][3] = fmaf(av.x, wv.w, acc[0][3]);
      acc[1][0] = fmaf(av.y, wv.x, acc[1][0]); acc[1][1] = fmaf(av.y, wv.y, acc[1][1]);
      acc[1][2] = fmaf(av.y, wv.z, acc[1][2]); acc[1][3] = fmaf(av.y, wv.w, acc[1][3]);
      acc[2][0] = fmaf(av.z, wv.x, acc[2][0]); acc[2][1] = fmaf(av.z, wv.y, acc[2][1]);
      acc[2][2] = fmaf(av.z, wv.z, acc[2][2]); acc[2][3] = fmaf(av.z, wv.w, acc[2][3]);
      acc[3][0] = fmaf(av.w, wv.x, acc[3][0]); acc[3][1] = fmaf(av.w, wv.y, acc[3][1]);
      acc[3][2] = fmaf(av.w, wv.z, acc[3][2]); acc[3][3] = fmaf(av.w, wv.w, acc[3][3]);
    }
    __syncthreads();
  }
  bool first = (blockIdx.y == 0);
#pragma unroll
  for (int i = 0; i < 4; ++i) {
    int row = (my << 2) + i;
#pragma unroll
    for (int j = 0; j < 4; ++j) {
      int col = n0 + (nx << 2) + j;
      float v = acc[i][j];
      if (first && bias0) v += bias0[col];
      atomicAdd(&C[(size_t)row * ldc + col], v);
    }
  }
}

// -- per-step h-GEMM: h@[Wdec -> F2 | Wfbeta(sigma) -> F2 | Whh+bih+bhh -> gates]
__global__ __launch_bounds__(256) void hgemm_step(
    const float* __restrict__ hprev, const float* __restrict__ Wdec,
    const float* __restrict__ bdec, const float* __restrict__ Wfb,
    const float* __restrict__ bfb, const float* __restrict__ Whh,
    const float* __restrict__ b_ih, const float* __restrict__ b_hh,
    float* __restrict__ F2, float* __restrict__ gates) {
  int cg0 = blockIdx.x * 32;  // [0, 4608)
  const float* W;
  const float* bias;
  const float* bias2 = nullptr;
  float* outp;
  int ostr, wcol, act, ldw, ocol;
  if (cg0 < ATTD) {
    W = Wdec; bias = bdec; wcol = cg0; act = 0; ldw = ATTD;
    outp = F2; ostr = F2STR; ocol = cg0;
  } else if (cg0 < ATTD + ENCD) {
    W = Wfb; bias = bfb; wcol = cg0 - ATTD; act = 1; ldw = ENCD;
    outp = F2; ostr = F2STR; ocol = cg0;
  } else {
    W = Whh; bias = b_ih; bias2 = b_hh; wcol = cg0 - (ATTD + ENCD); act = 0;
    ldw = 4 * DECD; outp = gates; ostr = 4 * DECD; ocol = wcol;
  }
  __shared__ __align__(16) float As[16][68];
  int tid = threadIdx.x;
  int my = tid >> 3, nx = tid & 7;  // 2 rows x 4 cols per thread
  int am = tid >> 2, ak = (tid & 3) << 2;
  float acc[2][4] = {};
  for (int k0 = 0; k0 < DECD; k0 += 16) {
    float4 a4 = *(const float4*)(hprev + (size_t)am * DECD + k0 + ak);
    As[ak + 0][am] = a4.x;
    As[ak + 1][am] = a4.y;
    As[ak + 2][am] = a4.z;
    As[ak + 3][am] = a4.w;
    __syncthreads();
    const float* wp = W + (size_t)k0 * ldw + wcol + (nx << 2);
#pragma unroll
    for (int kk = 0; kk < 16; ++kk) {
      float2 av = *(const float2*)&As[kk][my << 1];
      float4 wv = *(const float4*)(wp + (size_t)kk * ldw);
      acc[0][0] = fmaf(av.x, wv.x, acc[0][0]); acc[0][1] = fmaf(av.x, wv.y, acc[0][1]);
      acc[0][2] = fmaf(av.x, wv.z, acc[0][2]); acc[0][3] = fmaf(av.x, wv.w, acc[0][3]);
      acc[1][0] = fmaf(av.y, wv.x, acc[1][0]); acc[1][1] = fmaf(av.y, wv.y, acc[1][1]);
      acc[1][2] = fmaf(av.y, wv.z, acc[1][2]); acc[1][3] = fmaf(av.y, wv.w, acc[1][3]);
    }
    __syncthreads();
  }
#pragma unroll
  for (int i = 0; i < 2; ++i) {
    int row = (my << 1) + i;
#pragma unroll
    for (int j = 0; j < 4; ++j) {
      int cl = (nx << 2) + j;
      float v = acc[i][j] + bias[wcol + cl];
      if (bias2) v += bias2[wcol + cl];
      if (act) v = sigmoidf_(v);
      outp[(size_t)row * ostr + ocol + cl] = v;
    }
  }
}

// -------- score[b,p] = sum_a relu(att1+att2)*wf : one wave per (b,p) --------
__global__ __launch_bounds__(256) void score_kernel(const float* __restrict__ att1,
                                                    const float* __restrict__ F2,
                                                    const float* __restrict__ W_full,
                                                    float* __restrict__ scores) {
  int w = blockIdx.x * 4 + (threadIdx.x >> 6);  // [0, 12544)
  int lane = threadIdx.x & 63;
  int b = w / PP, p = w - b * PP;
  const float4* row = (const float4*)(att1 + ((size_t)b * PP + p) * ATTD) + (lane << 1);
  const float4* a2 = (const float4*)(F2 + (size_t)b * F2STR) + (lane << 1);
  const float4* w4 = (const float4*)W_full + (lane << 1);
  float acc = 0.f;
#pragma unroll
  for (int i = 0; i < 2; ++i) {
    float4 v = row[i], a = a2[i], wf = w4[i];
    acc = fmaf(fmaxf(v.x + a.x, 0.f), wf.x, acc);
    acc = fmaf(fmaxf(v.y + a.y, 0.f), wf.y, acc);
    acc = fmaf(fmaxf(v.z + a.z, 0.f), wf.z, acc);
    acc = fmaf(fmaxf(v.w + a.w, 0.f), wf.w, acc);
  }
#pragma unroll
  for (int off = 32; off; off >>= 1) acc += __shfl_down(acc, off);
  if (lane == 0) scores[b * PP + p] = acc;
}

// -------- softmax(196) per block + gated awe for a 256-wide e-slice ---------
__global__ __launch_bounds__(256) void awe_softmax_kernel(
    const float* __restrict__ scores, const float* __restrict__ F2,
    const float* __restrict__ enc, float* __restrict__ alphas_out,
    float* __restrict__ lstm_in, int t) {
  int b = blockIdx.y, et = blockIdx.x, tid = threadIdx.x;
  __shared__ __align__(16) float al[256];
  __shared__ float sc[256];
  __shared__ float red[256];
  float s = (tid < PP) ? scores[b * PP + tid] : -1e30f;
  sc[tid] = s;
  __syncthreads();
  for (int off = 128; off; off >>= 1) {
    if (tid < off) sc[tid] = fmaxf(sc[tid], sc[tid + off]);
    __syncthreads();
  }
  float e = (tid < PP) ? __expf(s - sc[0]) : 0.f;
  red[tid] = e;
  __syncthreads();
  for (int off = 128; off; off >>= 1) {
    if (tid < off) red[tid] += red[tid + off];
    __syncthreads();
  }
  float a = e * (1.f / red[0]);
  al[tid] = a;
  if (et == 0 && tid < PP)
    alphas_out[(size_t)b * (TDEC * PP) + (size_t)t * PP + tid] = a;
  __syncthreads();
  int e0 = et * 256 + tid;
  const float4* row = (const float4*)(enc + ((size_t)b * ENCD + e0) * PP);
  const float4* al4 = (const float4*)al;
  float acc = 0.f;
#pragma unroll 7
  for (int i = 0; i < PP / 4; ++i) {
    float4 v = row[i], aa = al4[i];
    acc = fmaf(v.x, aa.x, acc);
    acc = fmaf(v.y, aa.y, acc);
    acc = fmaf(v.z, aa.z, acc);
    acc = fmaf(v.w, aa.w, acc);
  }
  float gate = F2[(size_t)b * F2STR + ATTD + e0];
  lstm_in[(size_t)b * (EMBD + ENCD) + EMBD + e0] = gate * acc;
}

// -------- gates += lstm_in @ W_ih  (k-split atomic; biases+hh already there) -
__global__ __launch_bounds__(256) void gates_gemm(const float* __restrict__ A,
                                                  const float* __restrict__ W_ih,
                                                  float* __restrict__ gates) {
  const int K = EMBD + ENCD, N = 4 * DECD, kchunk = 512;
  __shared__ __align__(16) float As[16][68];
  int tid = threadIdx.x;
  int my = tid >> 3, nx = tid & 7;
  int am = tid >> 2, ak = (tid & 3) << 2;
  int n0 = blockIdx.x * 32;
  int k0s = blockIdx.y * kchunk, k0e = k0s + kchunk;
  float acc[2][4] = {};
  for (int k0 = k0s; k0 < k0e; k0 += 16) {
    float4 a4 = *(const float4*)(A + (size_t)am * K + k0 + ak);
    As[ak + 0][am] = a4.x;
    As[ak + 1][am] = a4.y;
    As[ak + 2][am] = a4.z;
    As[ak + 3][am] = a4.w;
    __syncthreads();
    const float* wp = W_ih + (size_t)k0 * N + n0 + (nx << 2);
#pragma unroll
    for (int kk = 0; kk < 16; ++kk) {
      float2 av = *(const float2*)&As[kk][my << 1];
      float4 wv = *(const float4*)(wp + (size_t)kk * N);
      acc[0][0] = fmaf(av.x, wv.x, acc[0][0]); acc[0][1] = fmaf(av.x, wv.y, acc[0][1]);
      acc[0][2] = fmaf(av.x, wv.z, acc[0][2]); acc[0][3] = fmaf(av.x, wv.w, acc[0][3]);
      acc[1][0] = fmaf(av.y, wv.x, acc[1][0]); acc[1][1] = fmaf(av.y, wv.y, acc[1][1]);
      acc[1][2] = fmaf(av.y, wv.z, acc[1][2]); acc[1][3] = fmaf(av.y, wv.w, acc[1][3]);
    }
    __syncthreads();
  }
#pragma unroll
  for (int i = 0; i < 2; ++i) {
    int row = (my << 1) + i;
#pragma unroll
    for (int j = 0; j < 4; ++j) {
      int col = n0 + (nx << 2) + j;
      atomicAdd(&gates[(size_t)row * N + col], acc[i][j]);
    }
  }
}

// ---- LSTM pointwise -> h into Hbuf slot; gathers next-step embedding -------
__global__ __launch_bounds__(256) void lstm_kernel(const float* __restrict__ gates,
                                                   float* __restrict__ c,
                                                   float* __restrict__ hout,
                                                   const int* __restrict__ captions,
                                                   const float* __restrict__ embedding,
                                                   float* __restrict__ lstm_in, int tn) {
  int idx = blockIdx.x * 256 + threadIdx.x;  // 0..32767
  int b = idx >> 9, d = idx & 511;
  const float* g = gates + (size_t)b * 2048;
  float gi = g[d], gf = g[d + 512], gg = g[d + 1024], go = g[d + 1536];
  float iv = sigmoidf_(gi);
  float fv = sigmoidf_(gf);
  float ov = sigmoidf_(go);
  float gv = tanhf(gg);
  float cn = fv * c[idx] + iv * gv;
  c[idx] = cn;
  hout[idx] = ov * tanhf(cn);
  int tok = captions[b * 21 + tn];
  lstm_in[(size_t)b * (EMBD + ENCD) + d] = embedding[(size_t)tok * EMBD + d];
}

// ---------------- t=0 embedding gather --------------------------------------
__global__ __launch_bounds__(256) void emb0_kernel(const int* __restrict__ captions,
                                                   const float* __restrict__ embedding,
                                                   float* __restrict__ lstm_in) {
  int idx = blockIdx.x * 256 + threadIdx.x;
  int b = idx >> 9, d = idx & 511;
  int tok = captions[b * 21];
  lstm_in[(size_t)b * (EMBD + ENCD) + d] = embedding[(size_t)tok * EMBD + d];
}

extern "C" void kernel_launch(void* const* d_in, const int* in_sizes, int n_in,
                              void* d_out, int out_size, void* d_ws, size_t ws_size,
                              hipStream_t stream) {
  const float* enc = (const float*)d_in[0];
  const int* captions = (const int*)d_in[1];
  const float* W_enc_att = (const float*)d_in[2];
  const float* b_enc_att = (const float*)d_in[3];
  const float* W_dec_att = (const float*)d_in[4];
  const float* b_dec_att = (const float*)d_in[5];
  const float* W_full = (const float*)d_in[6];
  const float* embedding = (const float*)d_in[8];
  const float* W_ih = (const float*)d_in[9];
  const float* W_hh = (const float*)d_in[10];
  const float* b_ih = (const float*)d_in[11];
  const float* b_hh = (const float*)d_in[12];
  const float* W_init_h = (const float*)d_in[13];
  const float* b_init_h = (const float*)d_in[14];
  const float* W_init_c = (const float*)d_in[15];
  const float* b_init_c = (const float*)d_in[16];
  const float* W_f_beta = (const float*)d_in[17];
  const float* b_f_beta = (const float*)d_in[18];
  const float* W_fc = (const float*)d_in[19];
  const float* b_fc = (const float*)d_in[20];

  float* out = (float*)d_out;
  float* preds = out;                             // 64*20*9490
  float* alphas = out + (size_t)BB * TDEC * VOC;  // 64*20*196
  // att1 aliases the preds region: dead before fc_mfma writes preds.
  float* att1 = preds;

  float* ws = (float*)d_ws;
  float* c = ws;                                // 32768
  float* F2 = c + BB * DECD;                    // 163840
  float* scores = F2 + BB * F2STR;              // 12544
  float* lstm_in = scores + BB * PP;            // 163840
  float* gates = lstm_in + BB * (EMBD + ENCD);  // 131072
  float* mean = gates + BB * 4 * DECD;          // 131072
  float* Hbuf = mean + BB * ENCD;               // 688128
  // split-bf16 weight copies (hi/lo, transposed [N][K]):
  u16* WTa_h = (u16*)(Hbuf + (size_t)(TDEC + 1) * BB * DECD);
  u16* WTa_l = WTa_h + (size_t)ATTD * ENCD;  // 512*2048 each
  u16* WTf_h = WTa_l + (size_t)ATTD * ENCD;
  u16* WTf_l = WTf_h + (size_t)NPAD * DECD;  // 9536*512 each
  // total ~29 MB

  hipMemsetAsync(c, 0, (size_t)BB * DECD * 4, stream);
  hipMemsetAsync(Hbuf, 0, (size_t)BB * DECD * 4, stream);  // h0 accumulator

  convT_kernel<<<dim3(ENCD / 64, ATTD / 64), 256, 0, stream>>>(W_enc_att, ENCD, ATTD,
                                                               WTa_h, WTa_l);
  convT_kernel<<<dim3(DECD / 64, (VOC + 63) / 64), 256, 0, stream>>>(W_fc, DECD, VOC,
                                                                     WTf_h, WTf_l);

  mean_kernel<<<BB * ENCD / 4, 256, 0, stream>>>(enc, mean);
  gemm64_atomic<<<dim3(DECD / 64, 4), 256, 0, stream>>>(mean, ENCD, W_init_h, DECD,
                                                        Hbuf, DECD, b_init_h, 512);
  gemm64_atomic<<<dim3(DECD / 64, 4), 256, 0, stream>>>(mean, ENCD, W_init_c, DECD, c,
                                                        DECD, b_init_c, 512);
  att1_mfma<<<dim3(ATTD / 64, (BB * PP) / 64), 256, 0, stream>>>(enc, WTa_h, WTa_l,
                                                                 b_enc_att, att1);
  emb0_kernel<<<BB * EMBD / 256, 256, 0, stream>>>(captions, embedding, lstm_in);

  for (int t = 0; t < TDEC; ++t) {
    const float* hprev = Hbuf + (size_t)t * BB * DECD;
    float* hnext = Hbuf + (size_t)(t + 1) * BB * DECD;
    hgemm_step<<<(ATTD + ENCD + 4 * DECD) / 32, 256, 0, stream>>>(
        hprev, W_dec_att, b_dec_att, W_f_beta, b_f_beta, W_hh, b_ih, b_hh, F2, gates);
    score_kernel<<<BB * PP / 4, 256, 0, stream>>>(att1, F2, W_full, scores);
    awe_softmax_kernel<<<dim3(ENCD / 256, BB), 256, 0, stream>>>(scores, F2, enc,
                                                                 alphas, lstm_in, t);
    gates_gemm<<<dim3(4 * DECD / 32, 5), 256, 0, stream>>>(lstm_in, W_ih, gates);
    lstm_kernel<<<BB * DECD / 256, 256, 0, stream>>>(gates, c, hnext, captions,
                                                     embedding, lstm_in, t + 1);
  }
  fc_mfma<<<dim3((VOC + 63) / 64, TDEC * BB / 64), 256, 0, stream>>>(
      Hbuf + BB * DECD, WTf_h, WTf_l, b_fc, preds);
}